// Round 9
// baseline (423.387 us; speedup 1.0000x reference)
//
#include <hip/hip_runtime.h>

#define N_NODES 50000
#define N_RELSR 20
#define R_TOT   41          // 2*N_RELSR + 1
#define N_EDGES 500000
#define EMB     16
#define NCLS    16
#define NB      40
#define E_TOT   (2 * N_EDGES + N_NODES)   // 1,050,000
#define NE_COL  (N_NODES * EMB)           // 800,000
#define NBLK_N  ((N_NODES + 255) / 256)   // 196

// f32 -> bf16 round-to-nearest-even (manual, no header dependency)
__device__ __forceinline__ unsigned short f2bf(float f) {
    unsigned u = __float_as_uint(f);
    u += 0x7FFFu + ((u >> 16) & 1u);
    return (unsigned short)(u >> 16);
}

// decode enriched edge i -> (s, o, r)
__device__ __forceinline__ void edge_decode(int i, const int* __restrict__ src,
                                            const int* __restrict__ dst,
                                            const int* __restrict__ rel,
                                            int& s, int& o, int& r) {
    if (i < N_EDGES) {
        s = src[i]; o = dst[i]; r = rel[i];
    } else if (i < 2 * N_EDGES) {
        int j = i - N_EDGES;
        s = dst[j]; o = src[j]; r = rel[j] + N_RELSR;
    } else {
        int n = i - 2 * N_EDGES;
        s = n; o = n; r = 2 * N_RELSR;
    }
}

// ---- Round-8 CSR build (streamlined) ---------------------------------------
// cnt is a plain int count (was int2 {count, r-prefix}): memset halves,
// k_degA reads 8.2MB and writes nothing back, rank[] (4.2MB w + 4.2MB r) is
// gone. k_fill gets its slot from atomicAdd(cursor[s]) where cursor is
// initialized to off[s] by k_degC. Within-segment order is nondeterministic;
// per-node sums of ~21 small terms -> reorder noise << absmax tolerance.

// ---- K1: segment counts ------------------------------------------------------
__global__ void k_count(const int* __restrict__ src, const int* __restrict__ dst,
                        const int* __restrict__ rel, int* __restrict__ cnt) {
    int i = blockIdx.x * blockDim.x + threadIdx.x;
    if (i >= E_TOT) return;
    int s, o, r;
    edge_decode(i, src, dst, rel, s, o, r);
    atomicAdd(&cnt[r * N_NODES + s], 1);
}

// ---- K2a: deg[s] = sum_r cnt[r,s]; per-block sums ---------------------------
__global__ void k_degA(const int* __restrict__ cnt, int* __restrict__ deg,
                       int* __restrict__ bsum) {
    __shared__ int red[256];
    int t = threadIdx.x;
    int s = blockIdx.x * 256 + t;
    int run = 0;
    if (s < N_NODES) {
        for (int r = 0; r < R_TOT; r++) run += cnt[r * N_NODES + s];
        deg[s] = run;
    }
    red[t] = run;
    __syncthreads();
    for (int st = 128; st > 0; st >>= 1) {
        if (t < st) red[t] += red[t + st];
        __syncthreads();
    }
    if (t == 0) bsum[blockIdx.x] = red[0];
}

// ---- K2b: exclusive scan of 196 block sums (single tiny block) --------------
__global__ void k_degB(int* __restrict__ bsum) {
    __shared__ int sh[256];
    int t = threadIdx.x;
    int v = (t < NBLK_N) ? bsum[t] : 0;
    sh[t] = v;
    __syncthreads();
    for (int d = 1; d < 256; d <<= 1) {
        int x = (t >= d) ? sh[t - d] : 0;
        __syncthreads();
        sh[t] += x;
        __syncthreads();
    }
    if (t < NBLK_N) bsum[t] = sh[t] - v;   // exclusive
}

// ---- K2c: block-local scan of deg -> off; cursor = off copy -----------------
__global__ void k_degC(const int* __restrict__ deg, const int* __restrict__ bsum,
                       int* __restrict__ off, int* __restrict__ cursor) {
    __shared__ int sh[256];
    int t = threadIdx.x;
    int s = blockIdx.x * 256 + t;
    int d = (s < N_NODES) ? deg[s] : 0;
    sh[t] = d;
    __syncthreads();
    for (int dd = 1; dd < 256; dd <<= 1) {
        int x = (t >= dd) ? sh[t - dd] : 0;
        __syncthreads();
        sh[t] += x;
        __syncthreads();
    }
    int excl = sh[t] - d + bsum[blockIdx.x];
    if (s < N_NODES) { off[s] = excl; cursor[s] = excl; }
    if (s == 0) off[N_NODES] = E_TOT;
}

// ---- K3: fill CSR records {(r<<16)|o, v} grouped by s (order-free) ----------
__global__ void k_fill(const int* __restrict__ src, const int* __restrict__ dst,
                       const int* __restrict__ rel, const int* __restrict__ cnt,
                       int* __restrict__ cursor, int2* __restrict__ recs) {
    int i = blockIdx.x * blockDim.x + threadIdx.x;
    if (i >= E_TOT) return;
    int s, o, r;
    edge_decode(i, src, dst, rel, s, o, r);
    float v = 1.0f / (float)cnt[r * N_NODES + s];
    int pos = atomicAdd(&cursor[s], 1);
    recs[pos] = make_int2((r << 16) | o, __float_as_int(v));
}

// ---- K4: w1[r,n,e] = sum_b comps1[r,b] * bases1[b,n,e]  -> bf16 -------------
// Round-7 form, plateaued at ~75us (stage->barrier chain structural; bank
// conflicts fixed: each thread stages one column's 8-k run with a single
// conflict-free ds_write_b128; 512-thread blocks for 32-wave/CU cap).
//   bt physical f16 idx = col*64 + ((kb ^ ((col>>1)&7))<<3) + ko
// Write+read use the same involution => self-consistent.
// D layout col=lane&15, row=(lane>>4)*4+reg [m89-verified, proven r4-r8].
typedef _Float16 f16x8 __attribute__((ext_vector_type(8)));
typedef float f32x4 __attribute__((ext_vector_type(4)));
#define CA_LD 65   // LDS leading-dim pad (bank spread)

__global__ void __launch_bounds__(512)
k_w1(const float* __restrict__ comps1, const float* __restrict__ bases1,
     unsigned short* __restrict__ w1) {
    __shared__ _Float16 ca[48 * CA_LD];                 // 6240 B
    __shared__ __align__(16) _Float16 bt[256 * 64];     // 32768 B
    int tid = threadIdx.x;
    int cb = blockIdx.x * 256;
    // stage comps1 (zero-padded 48x64)
    for (int q = tid; q < 48 * 64; q += 512) {
        int row = q >> 6, k = q & 63;
        float v = (row < R_TOT && k < NB) ? comps1[row * NB + k] : 0.f;
        ca[row * CA_LD + k] = (_Float16)v;
    }
    // stage bases1 tile: task = (col, kb). 8 coalesced f32 loads (lane->col
    // contiguous) + 1 conflict-free ds_write_b128 per task. 1280 tasks.
    for (int task = tid; task < 256 * 5; task += 512) {
        int col = task & 255;
        int kb  = task >> 8;             // 0..4
        int hash = (col >> 1) & 7;
        f16x8 pk;
#pragma unroll
        for (int j = 0; j < 8; j++)
            pk[j] = (_Float16)bases1[(size_t)(kb * 8 + j) * NE_COL + cb + col];
        *(f16x8*)(&bt[col * 64 + ((kb ^ hash) << 3)]) = pk;
    }
    __syncthreads();

    int lane = tid & 63, wave = tid >> 6;   // 8 waves
    int c0 = lane & 15;          // col-sub (t) / A-row (r)
    int g  = lane >> 4;          // k-group
    // A fragments: rows m*16+c0, k = q*32+g*8+j (ca zero-padded past NB/R_TOT)
    f16x8 af[3][2];
#pragma unroll
    for (int m = 0; m < 3; m++)
#pragma unroll
        for (int q = 0; q < 2; q++)
#pragma unroll
            for (int j = 0; j < 8; j++)
                af[m][q][j] = ca[(m * 16 + c0) * CA_LD + q * 32 + g * 8 + j];

#pragma unroll 1
    for (int it = 0; it < 2; it++) {
        int lcol = wave * 32 + it * 16 + c0;   // 0..255
        int col  = cb + lcol;
        int hash = (lcol >> 1) & 7;
        const _Float16* bp = &bt[lcol * 64];
        f16x8 b0 = *(const f16x8*)(bp + ((g ^ hash) << 3));     // k = g*8+j
        f16x8 b1;
#pragma unroll
        for (int j = 0; j < 8; j++) b1[j] = (_Float16)0.f;
        if (g == 0) b1 = *(const f16x8*)(bp + ((4 ^ hash) << 3)); // k = 32+j
        f32x4 d0 = {0.f, 0.f, 0.f, 0.f};
        f32x4 d1 = {0.f, 0.f, 0.f, 0.f};
        f32x4 d2 = {0.f, 0.f, 0.f, 0.f};
        d0 = __builtin_amdgcn_mfma_f32_16x16x32_f16(af[0][0], b0, d0, 0, 0, 0);
        d0 = __builtin_amdgcn_mfma_f32_16x16x32_f16(af[0][1], b1, d0, 0, 0, 0);
        d1 = __builtin_amdgcn_mfma_f32_16x16x32_f16(af[1][0], b0, d1, 0, 0, 0);
        d1 = __builtin_amdgcn_mfma_f32_16x16x32_f16(af[1][1], b1, d1, 0, 0, 0);
        d2 = __builtin_amdgcn_mfma_f32_16x16x32_f16(af[2][0], b0, d2, 0, 0, 0);
        d2 = __builtin_amdgcn_mfma_f32_16x16x32_f16(af[2][1], b1, d2, 0, 0, 0);
#pragma unroll
        for (int i = 0; i < 4; i++) {                // rows 0..15
            int row = g * 4 + i;
            w1[(size_t)row * NE_COL + col] = f2bf(d0[i]);
        }
#pragma unroll
        for (int i = 0; i < 4; i++) {                // rows 16..31
            int row = 16 + g * 4 + i;
            w1[(size_t)row * NE_COL + col] = f2bf(d1[i]);
        }
#pragma unroll
        for (int i = 0; i < 4; i++) {                // rows 32..40 (predicated)
            int row = 32 + g * 4 + i;
            if (row < R_TOT)
                w1[(size_t)row * NE_COL + col] = f2bf(d2[i]);
        }
    }
}

// ---- K5: w2p[r,c,ep] = packed bf16 pair (e=2ep, 2ep+1) of ---------------------
//          sum_b comps2[r,b] * bases2[b,e,c]
__global__ void k_w2(const float* __restrict__ comps2, const float* __restrict__ bases2,
                     unsigned* __restrict__ w2p) {
    int r = blockIdx.x;        // 41 blocks
    int t = threadIdx.x;       // 128 = NCLS*EMB/2, t = c*8+ep
    int c = t >> 3, ep = t & 7;
    int e0 = 2 * ep, e1 = 2 * ep + 1;
    float a0 = 0.f, a1 = 0.f;
#pragma unroll 8
    for (int b = 0; b < NB; b++) {
        float cc = comps2[r * NB + b];
        a0 = fmaf(cc, bases2[b * (EMB * NCLS) + e0 * NCLS + c], a0);
        a1 = fmaf(cc, bases2[b * (EMB * NCLS) + e1 * NCLS + c], a1);
    }
    w2p[r * 128 + t] = ((unsigned)f2bf(a1) << 16) | (unsigned)f2bf(a0);
}

// ---- K6: layer-1 gather, 8 lanes/edge, 8-edge unroll ------------------------
__global__ void k_l1_gather(const int* __restrict__ off, const int2* __restrict__ recs,
                            const unsigned* __restrict__ w1p,
                            const float* __restrict__ bias1, float* __restrict__ h) {
    int t = blockIdx.x * blockDim.x + threadIdx.x;     // N_NODES*8
    if (t >= N_NODES * 8) return;
    int s = t >> 3, e2 = t & 7;
    int beg = off[s], end = off[s + 1];
    float ax = 0.f, ay = 0.f;
    int j = beg;
    for (; j + 7 < end; j += 8) {
        int2 rc[8];
        unsigned p[8];
#pragma unroll
        for (int k = 0; k < 8; k++) rc[k] = recs[j + k];
#pragma unroll
        for (int k = 0; k < 8; k++)
            p[k] = w1p[(size_t)(rc[k].x >> 16) * (NE_COL / 2) + (rc[k].x & 0xFFFF) * 8 + e2];
#pragma unroll
        for (int k = 0; k < 8; k++) {
            float v = __int_as_float(rc[k].y);
            ax = fmaf(v, __uint_as_float(p[k] << 16), ax);
            ay = fmaf(v, __uint_as_float(p[k] & 0xFFFF0000u), ay);
        }
    }
    for (; j < end; j++) {
        int2 rc = recs[j];
        unsigned p = w1p[(size_t)(rc.x >> 16) * (NE_COL / 2) + (rc.x & 0xFFFF) * 8 + e2];
        float v = __int_as_float(rc.y);
        ax = fmaf(v, __uint_as_float(p << 16), ax);
        ay = fmaf(v, __uint_as_float(p & 0xFFFF0000u), ay);
    }
    float2 res;
    res.x = fmaxf(ax + bias1[2 * e2], 0.f);
    res.y = fmaxf(ay + bias1[2 * e2 + 1], 0.f);
    ((float2*)h)[t] = res;
}

// ---- K6-alt (fallback if ws too small for w1): on-the-fly basis contraction -
__global__ void k_l1_gather_fly(const int* __restrict__ off, const int2* __restrict__ recs,
                                const float* __restrict__ comps1,
                                const float* __restrict__ bases1,
                                const float* __restrict__ bias1, float* __restrict__ h) {
    __shared__ float c1[R_TOT * NB];
    for (int q = threadIdx.x; q < R_TOT * NB; q += blockDim.x) c1[q] = comps1[q];
    __syncthreads();
    int t = blockIdx.x * blockDim.x + threadIdx.x;
    int s = t >> 4, e = t & 15;
    int beg = off[s], end = off[s + 1];
    float acc = 0.f;
    for (int j = beg; j < end; j++) {
        int2 rec = recs[j];
        int o = rec.x & 0xFFFF, r = rec.x >> 16;
        float v = __int_as_float(rec.y);
        const float* cr = &c1[r * NB];
        float w = 0.f;
#pragma unroll 8
        for (int b = 0; b < NB; b++) w += cr[b] * bases1[(size_t)b * NE_COL + o * EMB + e];
        acc += v * w;
    }
    h[t] = fmaxf(acc + bias1[e], 0.f);
}

// ---- K7: layer-2 gather, bf16 w2 in LDS -------------------------------------
// All 16 lanes of an edge-group load the same 64B h[o,:] row (L1 broadcast).
// w2 stored as packed bf16 pairs: [r][c][ep], c-stride 10 uints (lane-c bank
// pattern c*10%32 covers all 16 banks), r-stride 164 uints. 26,896 B LDS ->
// 4 blocks of 512 per CU (~100% occupancy vs 47% with the 53KB f32 tile).
#define W2C2 10
#define W2R2 (16 * W2C2 + 4)    // 164 uints per relation
__device__ __forceinline__ float l2_edge(int2 ra, const float* __restrict__ h,
                                         const unsigned* w2s, int cbase) {
    const float4* ha = (const float4*)(h + (size_t)(ra.x & 0xFFFF) * EMB);
    const unsigned* base = &w2s[(ra.x >> 16) * W2R2 + cbase];
    float4 h0 = ha[0], h1 = ha[1], h2 = ha[2], h3 = ha[3];
    uint2 q0 = *(const uint2*)(base + 0);
    uint2 q1 = *(const uint2*)(base + 2);
    uint2 q2 = *(const uint2*)(base + 4);
    uint2 q3 = *(const uint2*)(base + 6);
    float da;
    da  = h0.x * __uint_as_float(q0.x << 16);
    da = fmaf(h0.y, __uint_as_float(q0.x & 0xFFFF0000u), da);
    da = fmaf(h0.z, __uint_as_float(q0.y << 16), da);
    da = fmaf(h0.w, __uint_as_float(q0.y & 0xFFFF0000u), da);
    da = fmaf(h1.x, __uint_as_float(q1.x << 16), da);
    da = fmaf(h1.y, __uint_as_float(q1.x & 0xFFFF0000u), da);
    da = fmaf(h1.z, __uint_as_float(q1.y << 16), da);
    da = fmaf(h1.w, __uint_as_float(q1.y & 0xFFFF0000u), da);
    da = fmaf(h2.x, __uint_as_float(q2.x << 16), da);
    da = fmaf(h2.y, __uint_as_float(q2.x & 0xFFFF0000u), da);
    da = fmaf(h2.z, __uint_as_float(q2.y << 16), da);
    da = fmaf(h2.w, __uint_as_float(q2.y & 0xFFFF0000u), da);
    da = fmaf(h3.x, __uint_as_float(q3.x << 16), da);
    da = fmaf(h3.y, __uint_as_float(q3.x & 0xFFFF0000u), da);
    da = fmaf(h3.z, __uint_as_float(q3.y << 16), da);
    da = fmaf(h3.w, __uint_as_float(q3.y & 0xFFFF0000u), da);
    return __int_as_float(ra.y) * da;
}

__global__ void k_l2_gather(const int* __restrict__ off, const int2* __restrict__ recs,
                            const float* __restrict__ h, const unsigned* __restrict__ w2p,
                            const float* __restrict__ bias2, float* __restrict__ out) {
    __shared__ __align__(16) unsigned w2s[R_TOT * W2R2];   // 26,896 B
    for (int q = threadIdx.x; q < R_TOT * 128; q += blockDim.x) {
        int r = q >> 7;
        int x = q & 127;
        int c = x >> 3, ep = x & 7;
        w2s[r * W2R2 + c * W2C2 + ep] = w2p[q];
    }
    __syncthreads();
    int t = blockIdx.x * blockDim.x + threadIdx.x;
    if (t >= NE_COL) return;
    int s = t >> 4, c = t & 15;
    int beg = off[s], end = off[s + 1];
    int cbase = c * W2C2;
    float acc = 0.f;
    int j = beg;
    for (; j + 3 < end; j += 4) {
        int2 r0 = recs[j], r1 = recs[j + 1], r2 = recs[j + 2], r3 = recs[j + 3];
        float t0 = l2_edge(r0, h, w2s, cbase);
        float t1 = l2_edge(r1, h, w2s, cbase);
        float t2 = l2_edge(r2, h, w2s, cbase);
        float t3 = l2_edge(r3, h, w2s, cbase);
        acc += (t0 + t1) + (t2 + t3);
    }
    for (; j < end; j++) {
        acc += l2_edge(recs[j], h, w2s, cbase);
    }
    out[s * NCLS + c] = acc + bias2[c];
}

static inline size_t align64(size_t x) { return (x + 63) & ~(size_t)63; }

extern "C" void kernel_launch(void* const* d_in, const int* in_sizes, int n_in,
                              void* d_out, int out_size, void* d_ws, size_t ws_size,
                              hipStream_t stream) {
    const int*   src    = (const int*)d_in[0];
    const int*   dst    = (const int*)d_in[1];
    const int*   rel    = (const int*)d_in[2];
    const float* comps1 = (const float*)d_in[3];
    const float* bases1 = (const float*)d_in[4];
    const float* comps2 = (const float*)d_in[5];
    const float* bases2 = (const float*)d_in[6];
    const float* bias1  = (const float*)d_in[7];
    const float* bias2  = (const float*)d_in[8];
    float* out = (float*)d_out;
    (void)in_sizes; (void)n_in; (void)out_size;

    char* ws = (char*)d_ws;
    size_t off_b = 0;
    // w1 (bf16, 65.6 MB) first; cnt (8.2MB) + cursor (0.2MB) alias its head
    // (both dead before k_w1 writes w1).
    unsigned short* w1 = (unsigned short*)ws;
    int*   cnt    = (int*)ws;
    int*   cursor = (int*)(ws + align64((size_t)R_TOT * N_NODES * 4));
    off_b = align64((size_t)R_TOT * NE_COL * 2);              // 65.6 MB
    int*      deg  = (int*)(ws + off_b);      off_b = align64(off_b + (size_t)N_NODES * 4);
    int*      off  = (int*)(ws + off_b);      off_b = align64(off_b + (size_t)(N_NODES + 1) * 4);
    int*      bsum = (int*)(ws + off_b);      off_b = align64(off_b + (size_t)256 * 4);
    int2*     recs = (int2*)(ws + off_b);     off_b = align64(off_b + (size_t)E_TOT * 8);
    float*    h    = (float*)(ws + off_b);    off_b = align64(off_b + (size_t)NE_COL * 4);
    unsigned* w2p  = (unsigned*)(ws + off_b); off_b = align64(off_b + (size_t)R_TOT * 128 * 4);
    const bool materialize_w1 = (ws_size >= off_b);
    if (!materialize_w1) {
        off_b = 0;
        cnt    = (int*)(ws + off_b);    off_b = align64(off_b + (size_t)R_TOT * N_NODES * 4);
        cursor = (int*)(ws + off_b);    off_b = align64(off_b + (size_t)N_NODES * 4);
        deg  = (int*)(ws + off_b);      off_b = align64(off_b + (size_t)N_NODES * 4);
        off  = (int*)(ws + off_b);      off_b = align64(off_b + (size_t)(N_NODES + 1) * 4);
        bsum = (int*)(ws + off_b);      off_b = align64(off_b + (size_t)256 * 4);
        recs = (int2*)(ws + off_b);     off_b = align64(off_b + (size_t)E_TOT * 8);
        h    = (float*)(ws + off_b);    off_b = align64(off_b + (size_t)NE_COL * 4);
        w2p  = (unsigned*)(ws + off_b); off_b = align64(off_b + (size_t)R_TOT * 128 * 4);
    }

    // zero counts
    hipMemsetAsync(cnt, 0, (size_t)R_TOT * N_NODES * 4, stream);

    const int BLK = 256;
    const int g_edge = (E_TOT + BLK - 1) / BLK;           // 4102
    const int g_w1   = NE_COL / 256;                      // 3125 (exact)
    const int g_l1   = (N_NODES * 8 + BLK - 1) / BLK;     // 1563
    const int g_l1f  = (N_NODES * 16) / BLK;              // 3125 (fallback, 16-lane)
    const int g_l2   = (NE_COL + 511) / 512;              // 1563

    k_count<<<g_edge, BLK, 0, stream>>>(src, dst, rel, cnt);
    k_degA<<<NBLK_N, 256, 0, stream>>>(cnt, deg, bsum);
    k_degB<<<1, 256, 0, stream>>>(bsum);
    k_degC<<<NBLK_N, 256, 0, stream>>>(deg, bsum, off, cursor);
    k_fill<<<g_edge, BLK, 0, stream>>>(src, dst, rel, cnt, cursor, recs);
    k_w2<<<R_TOT, 128, 0, stream>>>(comps2, bases2, w2p);

    if (materialize_w1) {
        k_w1<<<g_w1, 512, 0, stream>>>(comps1, bases1, w1);  // overwrites cnt/cursor (dead)
        k_l1_gather<<<g_l1, BLK, 0, stream>>>(off, recs, (const unsigned*)w1, bias1, h);
    } else {
        k_l1_gather_fly<<<g_l1f, BLK, 0, stream>>>(off, recs, comps1, bases1, bias1, h);
    }

    k_l2_gather<<<g_l2, 512, 0, stream>>>(off, recs, h, w2p, bias2, out);
}

// Round 10
// 405.372 us; speedup vs baseline: 1.0444x; 1.0444x over previous
//
#include <hip/hip_runtime.h>

#define N_NODES 50000
#define N_RELSR 20
#define R_TOT   41          // 2*N_RELSR + 1
#define N_EDGES 500000
#define EMB     16
#define NCLS    16
#define NB      40
#define E_TOT   (2 * N_EDGES + N_NODES)   // 1,050,000
#define NE_COL  (N_NODES * EMB)           // 800,000
#define NBLK_N  ((N_NODES + 255) / 256)   // 196

// f32 -> bf16 round-to-nearest-even (manual, no header dependency)
__device__ __forceinline__ unsigned short f2bf(float f) {
    unsigned u = __float_as_uint(f);
    u += 0x7FFFu + ((u >> 16) & 1u);
    return (unsigned short)(u >> 16);
}

// cnt2[idx] = { count, local r-prefix within node s }
// Round-9: r7/r8 deterministic CSR restored (r9's atomic-cursor fill was +18us).
// New: forward edge and its reverse share src/dst/rel loads -> one thread
// handles both (grid 4102 -> 2149 blocks, 12MB re-decode saved per kernel).

// ---- K1: segment counts; rank = slot within (r,s) segment -------------------
__global__ void k_count(const int* __restrict__ src, const int* __restrict__ dst,
                        const int* __restrict__ rel, int2* __restrict__ cnt2,
                        int* __restrict__ rank) {
    int t = blockIdx.x * blockDim.x + threadIdx.x;
    if (t >= N_EDGES + N_NODES) return;
    if (t < N_EDGES) {
        int s = src[t], o = dst[t], r = rel[t];
        rank[t] = atomicAdd(&cnt2[r * N_NODES + s].x, 1);
        rank[t + N_EDGES] = atomicAdd(&cnt2[(r + N_RELSR) * N_NODES + o].x, 1);
    } else {
        int n = t - N_EDGES;
        rank[2 * N_EDGES + n] = atomicAdd(&cnt2[2 * N_RELSR * N_NODES + n].x, 1);
    }
}

// ---- K2a: deg[s] = sum_r cnt[r,s]; local r-prefix into .y; per-block sums ---
__global__ void k_degA(int2* __restrict__ cnt2, int* __restrict__ deg,
                       int* __restrict__ bsum) {
    __shared__ int red[256];
    int t = threadIdx.x;
    int s = blockIdx.x * 256 + t;
    int run = 0;
    if (s < N_NODES) {
        for (int r = 0; r < R_TOT; r++) {
            int idx = r * N_NODES + s;
            int2 val = cnt2[idx];
            val.y = run;              // local exclusive prefix over r
            cnt2[idx] = val;
            run += val.x;
        }
        deg[s] = run;
    }
    red[t] = run;
    __syncthreads();
    for (int st = 128; st > 0; st >>= 1) {
        if (t < st) red[t] += red[t + st];
        __syncthreads();
    }
    if (t == 0) bsum[blockIdx.x] = red[0];
}

// ---- K2b: exclusive scan of 196 block sums (single tiny block) --------------
__global__ void k_degB(int* __restrict__ bsum) {
    __shared__ int sh[256];
    int t = threadIdx.x;
    int v = (t < NBLK_N) ? bsum[t] : 0;
    sh[t] = v;
    __syncthreads();
    for (int d = 1; d < 256; d <<= 1) {
        int x = (t >= d) ? sh[t - d] : 0;
        __syncthreads();
        sh[t] += x;
        __syncthreads();
    }
    if (t < NBLK_N) bsum[t] = sh[t] - v;   // exclusive
}

// ---- K2c: block-local scan of deg -> off (global CSR offsets) ---------------
__global__ void k_degC(const int* __restrict__ deg, const int* __restrict__ bsum,
                       int* __restrict__ off) {
    __shared__ int sh[256];
    int t = threadIdx.x;
    int s = blockIdx.x * 256 + t;
    int d = (s < N_NODES) ? deg[s] : 0;
    sh[t] = d;
    __syncthreads();
    for (int dd = 1; dd < 256; dd <<= 1) {
        int x = (t >= dd) ? sh[t - dd] : 0;
        __syncthreads();
        sh[t] += x;
        __syncthreads();
    }
    int excl = sh[t] - d + bsum[blockIdx.x];
    if (s < N_NODES) off[s] = excl;
    if (s == 0) off[N_NODES] = E_TOT;
}

// ---- K3: fill CSR records {(r<<16)|o, v} sorted by (s, r); no atomics -------
__global__ void k_fill(const int* __restrict__ src, const int* __restrict__ dst,
                       const int* __restrict__ rel, const int2* __restrict__ cnt2,
                       const int* __restrict__ rank, const int* __restrict__ off,
                       int2* __restrict__ recs) {
    int t = blockIdx.x * blockDim.x + threadIdx.x;
    if (t >= N_EDGES + N_NODES) return;
    if (t < N_EDGES) {
        int s = src[t], o = dst[t], r = rel[t];
        int2 cf = cnt2[r * N_NODES + s];
        recs[off[s] + cf.y + rank[t]] =
            make_int2((r << 16) | o, __float_as_int(1.0f / (float)cf.x));
        int rr = r + N_RELSR;
        int2 cb = cnt2[rr * N_NODES + o];
        recs[off[o] + cb.y + rank[t + N_EDGES]] =
            make_int2((rr << 16) | s, __float_as_int(1.0f / (float)cb.x));
    } else {
        int n = t - N_EDGES;
        int2 cl = cnt2[2 * N_RELSR * N_NODES + n];
        recs[off[n] + cl.y + rank[2 * N_EDGES + n]] =
            make_int2((2 * N_RELSR << 16) | n, __float_as_int(1.0f / (float)cl.x));
    }
}

// ---- K4: w1[r,n,e] = sum_b comps1[r,b] * bases1[b,n,e]  -> bf16 -------------
// Plateaued at ~76-79us across 4 structural variants (r5-r9): stage-latency ->
// barrier -> short-compute chain is structural at this shape; conflicts fixed
// (0.5M), occupancy 56%, all pipes <25% busy. CLOSED - do not touch.
//   bt physical f16 idx = col*64 + ((kb ^ ((col>>1)&7))<<3) + ko
// Write+read use the same involution => self-consistent.
// D layout col=lane&15, row=(lane>>4)*4+reg [m89-verified, proven r4-r9].
typedef _Float16 f16x8 __attribute__((ext_vector_type(8)));
typedef float f32x4 __attribute__((ext_vector_type(4)));
#define CA_LD 65   // LDS leading-dim pad (bank spread)

__global__ void __launch_bounds__(512)
k_w1(const float* __restrict__ comps1, const float* __restrict__ bases1,
     unsigned short* __restrict__ w1) {
    __shared__ _Float16 ca[48 * CA_LD];                 // 6240 B
    __shared__ __align__(16) _Float16 bt[256 * 64];     // 32768 B
    int tid = threadIdx.x;
    int cb = blockIdx.x * 256;
    // stage comps1 (zero-padded 48x64)
    for (int q = tid; q < 48 * 64; q += 512) {
        int row = q >> 6, k = q & 63;
        float v = (row < R_TOT && k < NB) ? comps1[row * NB + k] : 0.f;
        ca[row * CA_LD + k] = (_Float16)v;
    }
    // stage bases1 tile: task = (col, kb). 8 coalesced f32 loads (lane->col
    // contiguous) + 1 conflict-free ds_write_b128 per task. 1280 tasks.
    for (int task = tid; task < 256 * 5; task += 512) {
        int col = task & 255;
        int kb  = task >> 8;             // 0..4
        int hash = (col >> 1) & 7;
        f16x8 pk;
#pragma unroll
        for (int j = 0; j < 8; j++)
            pk[j] = (_Float16)bases1[(size_t)(kb * 8 + j) * NE_COL + cb + col];
        *(f16x8*)(&bt[col * 64 + ((kb ^ hash) << 3)]) = pk;
    }
    __syncthreads();

    int lane = tid & 63, wave = tid >> 6;   // 8 waves
    int c0 = lane & 15;          // col-sub (t) / A-row (r)
    int g  = lane >> 4;          // k-group
    // A fragments: rows m*16+c0, k = q*32+g*8+j (ca zero-padded past NB/R_TOT)
    f16x8 af[3][2];
#pragma unroll
    for (int m = 0; m < 3; m++)
#pragma unroll
        for (int q = 0; q < 2; q++)
#pragma unroll
            for (int j = 0; j < 8; j++)
                af[m][q][j] = ca[(m * 16 + c0) * CA_LD + q * 32 + g * 8 + j];

#pragma unroll 1
    for (int it = 0; it < 2; it++) {
        int lcol = wave * 32 + it * 16 + c0;   // 0..255
        int col  = cb + lcol;
        int hash = (lcol >> 1) & 7;
        const _Float16* bp = &bt[lcol * 64];
        f16x8 b0 = *(const f16x8*)(bp + ((g ^ hash) << 3));     // k = g*8+j
        f16x8 b1;
#pragma unroll
        for (int j = 0; j < 8; j++) b1[j] = (_Float16)0.f;
        if (g == 0) b1 = *(const f16x8*)(bp + ((4 ^ hash) << 3)); // k = 32+j
        f32x4 d0 = {0.f, 0.f, 0.f, 0.f};
        f32x4 d1 = {0.f, 0.f, 0.f, 0.f};
        f32x4 d2 = {0.f, 0.f, 0.f, 0.f};
        d0 = __builtin_amdgcn_mfma_f32_16x16x32_f16(af[0][0], b0, d0, 0, 0, 0);
        d0 = __builtin_amdgcn_mfma_f32_16x16x32_f16(af[0][1], b1, d0, 0, 0, 0);
        d1 = __builtin_amdgcn_mfma_f32_16x16x32_f16(af[1][0], b0, d1, 0, 0, 0);
        d1 = __builtin_amdgcn_mfma_f32_16x16x32_f16(af[1][1], b1, d1, 0, 0, 0);
        d2 = __builtin_amdgcn_mfma_f32_16x16x32_f16(af[2][0], b0, d2, 0, 0, 0);
        d2 = __builtin_amdgcn_mfma_f32_16x16x32_f16(af[2][1], b1, d2, 0, 0, 0);
#pragma unroll
        for (int i = 0; i < 4; i++) {                // rows 0..15
            int row = g * 4 + i;
            w1[(size_t)row * NE_COL + col] = f2bf(d0[i]);
        }
#pragma unroll
        for (int i = 0; i < 4; i++) {                // rows 16..31
            int row = 16 + g * 4 + i;
            w1[(size_t)row * NE_COL + col] = f2bf(d1[i]);
        }
#pragma unroll
        for (int i = 0; i < 4; i++) {                // rows 32..40 (predicated)
            int row = 32 + g * 4 + i;
            if (row < R_TOT)
                w1[(size_t)row * NE_COL + col] = f2bf(d2[i]);
        }
    }
}

// ---- K5: w2p[r,c,ep] = packed bf16 pair (e=2ep, 2ep+1) of ---------------------
//          sum_b comps2[r,b] * bases2[b,e,c]
__global__ void k_w2(const float* __restrict__ comps2, const float* __restrict__ bases2,
                     unsigned* __restrict__ w2p) {
    int r = blockIdx.x;        // 41 blocks
    int t = threadIdx.x;       // 128 = NCLS*EMB/2, t = c*8+ep
    int c = t >> 3, ep = t & 7;
    int e0 = 2 * ep, e1 = 2 * ep + 1;
    float a0 = 0.f, a1 = 0.f;
#pragma unroll 8
    for (int b = 0; b < NB; b++) {
        float cc = comps2[r * NB + b];
        a0 = fmaf(cc, bases2[b * (EMB * NCLS) + e0 * NCLS + c], a0);
        a1 = fmaf(cc, bases2[b * (EMB * NCLS) + e1 * NCLS + c], a1);
    }
    w2p[r * 128 + t] = ((unsigned)f2bf(a1) << 16) | (unsigned)f2bf(a0);
}

// ---- K6: layer-1 gather, 8 lanes/edge, 8-edge unroll ------------------------
__global__ void k_l1_gather(const int* __restrict__ off, const int2* __restrict__ recs,
                            const unsigned* __restrict__ w1p,
                            const float* __restrict__ bias1, float* __restrict__ h) {
    int t = blockIdx.x * blockDim.x + threadIdx.x;     // N_NODES*8
    if (t >= N_NODES * 8) return;
    int s = t >> 3, e2 = t & 7;
    int beg = off[s], end = off[s + 1];
    float ax = 0.f, ay = 0.f;
    int j = beg;
    for (; j + 7 < end; j += 8) {
        int2 rc[8];
        unsigned p[8];
#pragma unroll
        for (int k = 0; k < 8; k++) rc[k] = recs[j + k];
#pragma unroll
        for (int k = 0; k < 8; k++)
            p[k] = w1p[(size_t)(rc[k].x >> 16) * (NE_COL / 2) + (rc[k].x & 0xFFFF) * 8 + e2];
#pragma unroll
        for (int k = 0; k < 8; k++) {
            float v = __int_as_float(rc[k].y);
            ax = fmaf(v, __uint_as_float(p[k] << 16), ax);
            ay = fmaf(v, __uint_as_float(p[k] & 0xFFFF0000u), ay);
        }
    }
    for (; j < end; j++) {
        int2 rc = recs[j];
        unsigned p = w1p[(size_t)(rc.x >> 16) * (NE_COL / 2) + (rc.x & 0xFFFF) * 8 + e2];
        float v = __int_as_float(rc.y);
        ax = fmaf(v, __uint_as_float(p << 16), ax);
        ay = fmaf(v, __uint_as_float(p & 0xFFFF0000u), ay);
    }
    float2 res;
    res.x = fmaxf(ax + bias1[2 * e2], 0.f);
    res.y = fmaxf(ay + bias1[2 * e2 + 1], 0.f);
    ((float2*)h)[t] = res;
}

// ---- K6-alt (fallback if ws too small for w1): on-the-fly basis contraction -
__global__ void k_l1_gather_fly(const int* __restrict__ off, const int2* __restrict__ recs,
                                const float* __restrict__ comps1,
                                const float* __restrict__ bases1,
                                const float* __restrict__ bias1, float* __restrict__ h) {
    __shared__ float c1[R_TOT * NB];
    for (int q = threadIdx.x; q < R_TOT * NB; q += blockDim.x) c1[q] = comps1[q];
    __syncthreads();
    int t = blockIdx.x * blockDim.x + threadIdx.x;
    int s = t >> 4, e = t & 15;
    int beg = off[s], end = off[s + 1];
    float acc = 0.f;
    for (int j = beg; j < end; j++) {
        int2 rec = recs[j];
        int o = rec.x & 0xFFFF, r = rec.x >> 16;
        float v = __int_as_float(rec.y);
        const float* cr = &c1[r * NB];
        float w = 0.f;
#pragma unroll 8
        for (int b = 0; b < NB; b++) w += cr[b] * bases1[(size_t)b * NE_COL + o * EMB + e];
        acc += v * w;
    }
    h[t] = fmaxf(acc + bias1[e], 0.f);
}

// ---- K7: layer-2 gather, bf16 w2 in LDS -------------------------------------
// All 16 lanes of an edge-group load the same 64B h[o,:] row (L1 broadcast).
// w2 stored as packed bf16 pairs: [r][c][ep], c-stride 10 uints (lane-c bank
// pattern c*10%32 covers all 16 banks), r-stride 164 uints. 26,896 B LDS ->
// 4 blocks of 512 per CU (~100% occupancy vs 47% with the 53KB f32 tile).
#define W2C2 10
#define W2R2 (16 * W2C2 + 4)    // 164 uints per relation
__device__ __forceinline__ float l2_edge(int2 ra, const float* __restrict__ h,
                                         const unsigned* w2s, int cbase) {
    const float4* ha = (const float4*)(h + (size_t)(ra.x & 0xFFFF) * EMB);
    const unsigned* base = &w2s[(ra.x >> 16) * W2R2 + cbase];
    float4 h0 = ha[0], h1 = ha[1], h2 = ha[2], h3 = ha[3];
    uint2 q0 = *(const uint2*)(base + 0);
    uint2 q1 = *(const uint2*)(base + 2);
    uint2 q2 = *(const uint2*)(base + 4);
    uint2 q3 = *(const uint2*)(base + 6);
    float da;
    da  = h0.x * __uint_as_float(q0.x << 16);
    da = fmaf(h0.y, __uint_as_float(q0.x & 0xFFFF0000u), da);
    da = fmaf(h0.z, __uint_as_float(q0.y << 16), da);
    da = fmaf(h0.w, __uint_as_float(q0.y & 0xFFFF0000u), da);
    da = fmaf(h1.x, __uint_as_float(q1.x << 16), da);
    da = fmaf(h1.y, __uint_as_float(q1.x & 0xFFFF0000u), da);
    da = fmaf(h1.z, __uint_as_float(q1.y << 16), da);
    da = fmaf(h1.w, __uint_as_float(q1.y & 0xFFFF0000u), da);
    da = fmaf(h2.x, __uint_as_float(q2.x << 16), da);
    da = fmaf(h2.y, __uint_as_float(q2.x & 0xFFFF0000u), da);
    da = fmaf(h2.z, __uint_as_float(q2.y << 16), da);
    da = fmaf(h2.w, __uint_as_float(q2.y & 0xFFFF0000u), da);
    da = fmaf(h3.x, __uint_as_float(q3.x << 16), da);
    da = fmaf(h3.y, __uint_as_float(q3.x & 0xFFFF0000u), da);
    da = fmaf(h3.z, __uint_as_float(q3.y << 16), da);
    da = fmaf(h3.w, __uint_as_float(q3.y & 0xFFFF0000u), da);
    return __int_as_float(ra.y) * da;
}

__global__ void k_l2_gather(const int* __restrict__ off, const int2* __restrict__ recs,
                            const float* __restrict__ h, const unsigned* __restrict__ w2p,
                            const float* __restrict__ bias2, float* __restrict__ out) {
    __shared__ __align__(16) unsigned w2s[R_TOT * W2R2];   // 26,896 B
    for (int q = threadIdx.x; q < R_TOT * 128; q += blockDim.x) {
        int r = q >> 7;
        int x = q & 127;
        int c = x >> 3, ep = x & 7;
        w2s[r * W2R2 + c * W2C2 + ep] = w2p[q];
    }
    __syncthreads();
    int t = blockIdx.x * blockDim.x + threadIdx.x;
    if (t >= NE_COL) return;
    int s = t >> 4, c = t & 15;
    int beg = off[s], end = off[s + 1];
    int cbase = c * W2C2;
    float acc = 0.f;
    int j = beg;
    for (; j + 3 < end; j += 4) {
        int2 r0 = recs[j], r1 = recs[j + 1], r2 = recs[j + 2], r3 = recs[j + 3];
        float t0 = l2_edge(r0, h, w2s, cbase);
        float t1 = l2_edge(r1, h, w2s, cbase);
        float t2 = l2_edge(r2, h, w2s, cbase);
        float t3 = l2_edge(r3, h, w2s, cbase);
        acc += (t0 + t1) + (t2 + t3);
    }
    for (; j < end; j++) {
        acc += l2_edge(recs[j], h, w2s, cbase);
    }
    out[s * NCLS + c] = acc + bias2[c];
}

static inline size_t align64(size_t x) { return (x + 63) & ~(size_t)63; }

extern "C" void kernel_launch(void* const* d_in, const int* in_sizes, int n_in,
                              void* d_out, int out_size, void* d_ws, size_t ws_size,
                              hipStream_t stream) {
    const int*   src    = (const int*)d_in[0];
    const int*   dst    = (const int*)d_in[1];
    const int*   rel    = (const int*)d_in[2];
    const float* comps1 = (const float*)d_in[3];
    const float* bases1 = (const float*)d_in[4];
    const float* comps2 = (const float*)d_in[5];
    const float* bases2 = (const float*)d_in[6];
    const float* bias1  = (const float*)d_in[7];
    const float* bias2  = (const float*)d_in[8];
    float* out = (float*)d_out;
    (void)in_sizes; (void)n_in; (void)out_size;

    char* ws = (char*)d_ws;
    size_t off_b = 0;
    // w1 (bf16, 65.6 MB) first; cnt2 (16.4MB) + rank (4.2MB) alias its head
    // (both dead before k_w1 writes w1).
    unsigned short* w1 = (unsigned short*)ws;
    int2*  cnt2 = (int2*)ws;
    int*   rank = (int*)(ws + align64((size_t)R_TOT * N_NODES * 8));
    off_b = align64((size_t)R_TOT * NE_COL * 2);              // 65.6 MB
    int*      deg  = (int*)(ws + off_b);      off_b = align64(off_b + (size_t)N_NODES * 4);
    int*      off  = (int*)(ws + off_b);      off_b = align64(off_b + (size_t)(N_NODES + 1) * 4);
    int*      bsum = (int*)(ws + off_b);      off_b = align64(off_b + (size_t)256 * 4);
    int2*     recs = (int2*)(ws + off_b);     off_b = align64(off_b + (size_t)E_TOT * 8);
    float*    h    = (float*)(ws + off_b);    off_b = align64(off_b + (size_t)NE_COL * 4);
    unsigned* w2p  = (unsigned*)(ws + off_b); off_b = align64(off_b + (size_t)R_TOT * 128 * 4);
    const bool materialize_w1 = (ws_size >= off_b);
    if (!materialize_w1) {
        off_b = 0;
        cnt2 = (int2*)(ws + off_b);     off_b = align64(off_b + (size_t)R_TOT * N_NODES * 8);
        rank = (int*)(ws + off_b);      off_b = align64(off_b + (size_t)E_TOT * 4);
        deg  = (int*)(ws + off_b);      off_b = align64(off_b + (size_t)N_NODES * 4);
        off  = (int*)(ws + off_b);      off_b = align64(off_b + (size_t)(N_NODES + 1) * 4);
        bsum = (int*)(ws + off_b);      off_b = align64(off_b + (size_t)256 * 4);
        recs = (int2*)(ws + off_b);     off_b = align64(off_b + (size_t)E_TOT * 8);
        h    = (float*)(ws + off_b);    off_b = align64(off_b + (size_t)NE_COL * 4);
        w2p  = (unsigned*)(ws + off_b); off_b = align64(off_b + (size_t)R_TOT * 128 * 4);
    }

    // zero counts (.x of cnt2; .y overwritten by k_degA)
    hipMemsetAsync(cnt2, 0, (size_t)R_TOT * N_NODES * 8, stream);

    const int BLK = 256;
    const int g_pair = (N_EDGES + N_NODES + BLK - 1) / BLK;   // 2149
    const int g_w1   = NE_COL / 256;                      // 3125 (exact)
    const int g_l1   = (N_NODES * 8 + BLK - 1) / BLK;     // 1563
    const int g_l1f  = (N_NODES * 16) / BLK;              // 3125 (fallback, 16-lane)
    const int g_l2   = (NE_COL + 511) / 512;              // 1563

    k_count<<<g_pair, BLK, 0, stream>>>(src, dst, rel, cnt2, rank);
    k_degA<<<NBLK_N, 256, 0, stream>>>(cnt2, deg, bsum);
    k_degB<<<1, 256, 0, stream>>>(bsum);
    k_degC<<<NBLK_N, 256, 0, stream>>>(deg, bsum, off);
    k_fill<<<g_pair, BLK, 0, stream>>>(src, dst, rel, cnt2, rank, off, recs);
    k_w2<<<R_TOT, 128, 0, stream>>>(comps2, bases2, w2p);

    if (materialize_w1) {
        k_w1<<<g_w1, 512, 0, stream>>>(comps1, bases1, w1);  // overwrites cnt2/rank (dead)
        k_l1_gather<<<g_l1, BLK, 0, stream>>>(off, recs, (const unsigned*)w1, bias1, h);
    } else {
        k_l1_gather_fly<<<g_l1f, BLK, 0, stream>>>(off, recs, comps1, bases1, bias1, h);
    }

    k_l2_gather<<<g_l2, 512, 0, stream>>>(off, recs, h, w2p, bias2, out);
}